// Round 6
// baseline (409.387 us; speedup 1.0000x reference)
//
#include <hip/hip_runtime.h>
#include <stdint.h>

#define BATCH 8192
#define IN 4096
#define OUT 4096
#define EPS 1e-4f
#define RCHUNK 128
#define NCHUNKS (BATCH / RCHUNK)   // 64

typedef int v4i __attribute__((ext_vector_type(4)));
typedef unsigned char u8;

#define AS1(p) ((const __attribute__((address_space(1))) void*)(p))
#define AS3(p) ((__attribute__((address_space(3))) void*)(p))

// ---------------- Kernel 1: partial column sums (S1, S2), float4 ----------------
__global__ __launch_bounds__(256) void colstat_partial(
    const float* __restrict__ x, float* __restrict__ P1, float* __restrict__ P2) {
    int c4 = blockIdx.x * 256 + threadIdx.x;   // float4 column index 0..1023
    int r0 = blockIdx.y * RCHUNK;
    float4 s1 = {0.f, 0.f, 0.f, 0.f}, s2 = {0.f, 0.f, 0.f, 0.f};
    const float4* p = (const float4*)x + (size_t)r0 * (IN / 4) + c4;
#pragma unroll 8
    for (int r = 0; r < RCHUNK; ++r) {
        float4 v = p[(size_t)r * (IN / 4)];
        s1.x += v.x; s1.y += v.y; s1.z += v.z; s1.w += v.w;
        s2.x += v.x * v.x; s2.y += v.y * v.y; s2.z += v.z * v.z; s2.w += v.w * v.w;
    }
    ((float4*)P1)[blockIdx.y * (IN / 4) + c4] = s1;
    ((float4*)P2)[blockIdx.y * (IN / 4) + c4] = s2;
}

// ---------------- Kernel 2: finalize mu, a = rstd*gamma ----------------
__global__ __launch_bounds__(256) void colstat_final(
    const float* __restrict__ P1, const float* __restrict__ P2,
    const float* __restrict__ gamma, float* __restrict__ mu, float* __restrict__ aArr) {
    int col = blockIdx.x * 256 + threadIdx.x;
    double s1 = 0.0, s2 = 0.0;
#pragma unroll 4
    for (int c = 0; c < NCHUNKS; ++c) {
        s1 += (double)P1[c * IN + col];
        s2 += (double)P2[c * IN + col];
    }
    double m = s1 / (double)BATCH;
    double var = s2 / (double)BATCH - m * m;
    float rstd = (float)(1.0 / sqrt(var + (double)EPS));
    mu[col] = (float)m;
    aArr[col] = rstd * gamma[col];
}

// ---------------- Kernel 3: fused binarize of weight (blocks 0..OUT-1) and x
// (blocks OUT..OUT+BATCH-1). Bit-identical per-block programs.
__global__ __launch_bounds__(256) void binxw(
    const float* __restrict__ x, const float* __restrict__ mu,
    const float* __restrict__ aArr, const float* __restrict__ beta,
    const float* __restrict__ w,
    u8* __restrict__ x01, int* __restrict__ px,
    u8* __restrict__ w01, float* __restrict__ scale, int* __restrict__ pw) {
    __shared__ double redd[4];
    __shared__ int redi[4];
    __shared__ double bcast;
    int tid = threadIdx.x;
    int lane = tid & 63;
    int wv = tid >> 6;

    if (blockIdx.x < OUT) {
        // ---- weight path ----
        int o = blockIdx.x;
        const float4* row = (const float4*)(w + (size_t)o * IN);
        uchar4* o4 = (uchar4*)(w01 + (size_t)o * IN);

        float4 vs[4];
        float part = 0.f;
#pragma unroll
        for (int it = 0; it < 4; ++it) {
            vs[it] = row[it * 256 + tid];
            part += vs[it].x + vs[it].y + vs[it].z + vs[it].w;
        }
        double d = (double)part;
        for (int off = 32; off > 0; off >>= 1) d += __shfl_down(d, off, 64);
        if (lane == 0) redd[wv] = d;
        __syncthreads();
        if (tid == 0) bcast = (redd[0] + redd[1] + redd[2] + redd[3]) / (double)IN;
        __syncthreads();
        float mean = (float)bcast;

        float absacc = 0.f;
        int cnt = 0;
#pragma unroll
        for (int it = 0; it < 4; ++it) {
            float4 v = vs[it];
            float wcx = v.x - mean, wcy = v.y - mean, wcz = v.z - mean, wcw = v.w - mean;
            uchar4 ob;
            ob.x = (u8)(wcx > 0.f);
            ob.y = (u8)(wcy > 0.f);
            ob.z = (u8)(wcz > 0.f);
            ob.w = (u8)(wcw > 0.f);
            cnt += (int)ob.x + (int)ob.y + (int)ob.z + (int)ob.w;
            absacc += fminf(fabsf(wcx), 1.0f) + fminf(fabsf(wcy), 1.0f) +
                      fminf(fabsf(wcz), 1.0f) + fminf(fabsf(wcw), 1.0f);
            o4[it * 256 + tid] = ob;
        }
        double da = (double)absacc;
        for (int off = 32; off > 0; off >>= 1) da += __shfl_down(da, off, 64);
        for (int off = 32; off > 0; off >>= 1) cnt += __shfl_down(cnt, off, 64);
        if (lane == 0) { redd[wv] = da; redi[wv] = cnt; }
        __syncthreads();
        if (tid == 0) {
            scale[o] = (float)((redd[0] + redd[1] + redd[2] + redd[3]) / (double)IN);
            pw[o] = redi[0] + redi[1] + redi[2] + redi[3];
        }
    } else {
        // ---- activation path ----
        int r = blockIdx.x - OUT;
        const float4* row = (const float4*)(x + (size_t)r * IN);
        const float4* m4 = (const float4*)mu;
        const float4* a4 = (const float4*)aArr;
        const float4* b4 = (const float4*)beta;
        uchar4* o4 = (uchar4*)(x01 + (size_t)r * IN);
        int cnt = 0;
#pragma unroll
        for (int it = 0; it < IN / 1024; ++it) {   // 4 iters
            int q = it * 256 + tid;
            float4 v = row[q];
            float4 m = m4[q];
            float4 a = a4[q];
            float4 b = b4[q];
            uchar4 ob;
            ob.x = (u8)((v.x - m.x) * a.x + b.x > 0.f);
            ob.y = (u8)((v.y - m.y) * a.y + b.y > 0.f);
            ob.z = (u8)((v.z - m.z) * a.z + b.z > 0.f);
            ob.w = (u8)((v.w - m.w) * a.w + b.w > 0.f);
            cnt += (int)ob.x + (int)ob.y + (int)ob.z + (int)ob.w;
            o4[q] = ob;
        }
        for (int off = 32; off > 0; off >>= 1) cnt += __shfl_down(cnt, off, 64);
        if (lane == 0) redi[wv] = cnt;
        __syncthreads();
        if (tid == 0) px[r] = redi[0] + redi[1] + redi[2] + redi[3];
    }
}

// ---------------- Kernel 4: i8 MFMA GEMM, 256x256 tile, merged-region pipeline ----
// NEW STRUCTURE vs R5 (which measured LDS-reads and MFMA strictly serialized by
// the 2-barrier phases): ONE barrier region per K-tile of 64 bytes, containing
//   reads(t): 12 ds_read_b128  |  STG(t+3): 4 global_load_lds  |  32 MFMA
// Compiler-counted lgkmcnt lets early MFMAs run while later ds_reads stream ->
// LDS pipe overlaps MFMA pipe. 4 LDS buffers (32 KiB each, K-step 64 B) so the
// region's staging target (buf (t+3)&3) is never the region's read buffer
// (buf t&3) nor the previous region's (buf (t-1)&3 == (t+3)&3 was fully
// consumed before this region's barrier -- reads are lgkm-drained before their
// MMA, which precedes the barrier).
// vmcnt FIFO ladder: each region issues 4 loads/thread; at region end 12
// outstanding; VM(8) retires tile t+1 before the barrier that precedes its
// reads. Tail: VM(8)/VM(4)/VM(0). Read swizzle for 64-B rows:
// slot ^= (row&3)^((row>>2)&3) -> 2 lanes/bank (free); involution applied on
// staging SOURCE (LDS dest linear, required by global_load_lds) and read addr.
// dot_{+-1} = 4*acc - 2*px[r] - 2*pw[c] + IN
#define BK2 64
#define NT2 (IN / BK2)     // 64

#define STG2_A(t, q) __builtin_amdgcn_global_load_lds( \
    AS1(ag + (size_t)((q)*128 + slr2) * IN + (t)*BK2 + sswz2), \
    AS3(lds + ((t)&3)*32768 + (q)*8192 + sdst2), 16, 0, 0)
#define STG2_B(t, q) __builtin_amdgcn_global_load_lds( \
    AS1(bg + (size_t)((q)*128 + slr2) * IN + (t)*BK2 + sswz2), \
    AS3(lds + ((t)&3)*32768 + 16384 + (q)*8192 + sdst2), 16, 0, 0)
#define STG2(t) do { STG2_A(t,0); STG2_A(t,1); STG2_B(t,0); STG2_B(t,1); } while (0)

#define RD(t) do { \
    const u8* bp_ = lds + ((t)&3)*32768; \
    _Pragma("unroll") for (int j_ = 0; j_ < 4; ++j_) \
        bf[j_] = *(const v4i*)(bp_ + bB + j_*1024); \
    _Pragma("unroll") for (int i_ = 0; i_ < 8; ++i_) \
        af[i_] = *(const v4i*)(bp_ + aB + i_*1024); \
} while (0)

#define MMA2() do { \
    __builtin_amdgcn_s_setprio(1); \
    _Pragma("unroll") for (int i_ = 0; i_ < 8; ++i_) \
    _Pragma("unroll") for (int j_ = 0; j_ < 4; ++j_) \
        acc[i_][j_] = __builtin_amdgcn_mfma_i32_16x16x64_i8( \
            af[i_], bf[j_], acc[i_][j_], 0, 0, 0); \
    __builtin_amdgcn_s_setprio(0); \
} while (0)

#define BAR() asm volatile("s_barrier" ::: "memory")
#define VM(n) asm volatile("s_waitcnt vmcnt(" #n ")" ::: "memory")

__global__ __launch_bounds__(512, 2) void bgemm_i8(
    const u8* __restrict__ x01, const u8* __restrict__ w01,
    const int* __restrict__ px, const int* __restrict__ pw,
    const float* __restrict__ scale, const float* __restrict__ bias,
    float* __restrict__ out) {
    __shared__ u8 lds[131072];   // 4 bufs x (A 16K + B 16K)

    int tid = threadIdx.x;
    int lane = tid & 63;
    int wave = tid >> 6;          // 0..7
    int wm = wave >> 2;           // 0..1  (row half: 128 rows)
    int wn = wave & 3;            // 0..3  (col quarter: 64 cols)

    // XCD-aware block swizzle (512 blocks, 512%8==0 -> bijective)
    int lin = blockIdx.y * (OUT / 256) + blockIdx.x;   // 0..511
    int swz = (lin & 7) * 64 + (lin >> 3);
    int colBlk = (swz & 15) * 256;
    int rowBlk = (swz >> 4) * 256;

    const u8* ag = x01 + (size_t)rowBlk * IN;
    const u8* bg = w01 + (size_t)colBlk * IN;

    // staging constants: unit = 128 rows x 64 B; linear LDS dest, swizzled src
    int slr2 = tid >> 2;                               // row in unit 0..127
    int ss2 = tid & 3;                                 // 16B slot 0..3
    int sxor = (slr2 & 3) ^ ((slr2 >> 2) & 3);
    int sswz2 = (ss2 ^ sxor) * 16;                     // swizzled source offset
    int sdst2 = slr2 * 64 + ss2 * 16;                  // linear LDS offset

    // read constants: row-frag reads at swizzled slot
    int lrow = lane & 15;
    int lhi = lane >> 4;
    int rxor = (lrow & 3) ^ ((lrow >> 2) & 3);
    int swk2 = (lhi ^ rxor) * 16;
    int aB = (wm * 128 + lrow) * 64 + swk2;            // within A region
    int bB = 16384 + (wn * 64 + lrow) * 64 + swk2;     // within buf

    v4i acc[8][4];
#pragma unroll
    for (int i = 0; i < 8; ++i)
#pragma unroll
        for (int j = 0; j < 4; ++j) acc[i][j] = (v4i){0, 0, 0, 0};
    v4i af[8], bf[4];

    // ---- prologue: stage tiles 0,1,2; retire tile 0 ----
    STG2(0); STG2(1); STG2(2);
    VM(8);
    BAR();

    // ---- steady: t = 0..59 (unroll 4: buf indices compile-time) ----
    for (int tt = 0; tt < 15; ++tt) {
        int t0 = tt * 4;
#pragma unroll
        for (int u = 0; u < 4; ++u) {
            int t = t0 + u;
            RD(t);
            STG2(t + 3);
            MMA2();
            VM(8);
            BAR();
        }
    }
    // t = 60 (stages last tile 63)
    RD(60); STG2(63); MMA2(); VM(8); BAR();
    // t = 61
    RD(61); MMA2(); VM(4); BAR();
    // t = 62
    RD(62); MMA2(); VM(0); BAR();
    // t = 63
    RD(63); MMA2();

    // ---- epilogue ----
    int crow0 = lhi * 4;
    int ccol = lrow;
#pragma unroll
    for (int i = 0; i < 8; ++i) {
        int rbase = rowBlk + wm * 128 + i * 16 + crow0;
        int pxr[4];
#pragma unroll
        for (int rg = 0; rg < 4; ++rg) pxr[rg] = px[rbase + rg];
#pragma unroll
        for (int j = 0; j < 4; ++j) {
            int cb = colBlk + wn * 64 + j * 16 + ccol;
            float sc = scale[cb];
            float bs = bias[cb];
            int pwc = pw[cb];
#pragma unroll
            for (int rg = 0; rg < 4; ++rg) {
                int dot = 4 * acc[i][j][rg] - 2 * pxr[rg] - 2 * pwc + IN;
                float y = ((float)dot + bs) * sc;
                out[(size_t)(rbase + rg) * OUT + cb] = y > 0.f ? y : 0.f;
            }
        }
    }
}

extern "C" void kernel_launch(void* const* d_in, const int* in_sizes, int n_in,
                              void* d_out, int out_size, void* d_ws, size_t ws_size,
                              hipStream_t stream) {
    const float* x = (const float*)d_in[0];
    const float* gamma = (const float*)d_in[1];
    const float* beta = (const float*)d_in[2];
    const float* weight = (const float*)d_in[3];
    const float* bias = (const float*)d_in[4];
    float* out = (float*)d_out;

    char* w = (char*)d_ws;
    float* mu = (float*)(w);                    // 16 KB
    float* aArr = (float*)(w + 16384);          // 16 KB
    float* scale = (float*)(w + 32768);         // 16 KB
    int* px = (int*)(w + 49152);                // 32 KB
    int* pw = (int*)(w + 81920);                // 16 KB
    float* P1 = (float*)(w + (1 << 20));        // 1 MB
    float* P2 = (float*)(w + (2 << 20));        // 1 MB
    u8* x01 = (u8*)(w + (4 << 20));             // 32 MB
    u8* w01 = (u8*)(w + (36 << 20));            // 16 MB  (total 52 MB)

    colstat_partial<<<dim3(IN / 1024, NCHUNKS), 256, 0, stream>>>(x, P1, P2);
    colstat_final<<<dim3(IN / 256), 256, 0, stream>>>(P1, P2, gamma, mu, aArr);
    binxw<<<dim3(OUT + BATCH), 256, 0, stream>>>(x, mu, aArr, beta, weight,
                                                 x01, px, w01, scale, pw);
    bgemm_i8<<<dim3(OUT / 256, BATCH / 256), 512, 0, stream>>>(x01, w01, px, pw, scale, bias, out);
}

// Round 7
// 403.611 us; speedup vs baseline: 1.0143x; 1.0143x over previous
//
#include <hip/hip_runtime.h>
#include <stdint.h>

#define BATCH 8192
#define IN 4096
#define OUT 4096
#define EPS 1e-4f
#define RCHUNK 128
#define NCHUNKS (BATCH / RCHUNK)   // 64

typedef int v4i __attribute__((ext_vector_type(4)));
typedef unsigned char u8;

#define AS1(p) ((const __attribute__((address_space(1))) void*)(p))
#define AS3(p) ((__attribute__((address_space(3))) void*)(p))

// ---------------- Kernel 1: partial column sums (S1, S2), float4 ----------------
__global__ __launch_bounds__(256) void colstat_partial(
    const float* __restrict__ x, float* __restrict__ P1, float* __restrict__ P2) {
    int c4 = blockIdx.x * 256 + threadIdx.x;   // float4 column index 0..1023
    int r0 = blockIdx.y * RCHUNK;
    float4 s1 = {0.f, 0.f, 0.f, 0.f}, s2 = {0.f, 0.f, 0.f, 0.f};
    const float4* p = (const float4*)x + (size_t)r0 * (IN / 4) + c4;
#pragma unroll 8
    for (int r = 0; r < RCHUNK; ++r) {
        float4 v = p[(size_t)r * (IN / 4)];
        s1.x += v.x; s1.y += v.y; s1.z += v.z; s1.w += v.w;
        s2.x += v.x * v.x; s2.y += v.y * v.y; s2.z += v.z * v.z; s2.w += v.w * v.w;
    }
    ((float4*)P1)[blockIdx.y * (IN / 4) + c4] = s1;
    ((float4*)P2)[blockIdx.y * (IN / 4) + c4] = s2;
}

// ---------------- Kernel 2: finalize mu, a = rstd*gamma ----------------
__global__ __launch_bounds__(256) void colstat_final(
    const float* __restrict__ P1, const float* __restrict__ P2,
    const float* __restrict__ gamma, float* __restrict__ mu, float* __restrict__ aArr) {
    int col = blockIdx.x * 256 + threadIdx.x;
    double s1 = 0.0, s2 = 0.0;
#pragma unroll 4
    for (int c = 0; c < NCHUNKS; ++c) {
        s1 += (double)P1[c * IN + col];
        s2 += (double)P2[c * IN + col];
    }
    double m = s1 / (double)BATCH;
    double var = s2 / (double)BATCH - m * m;
    float rstd = (float)(1.0 / sqrt(var + (double)EPS));
    mu[col] = (float)m;
    aArr[col] = rstd * gamma[col];
}

// ---------------- Kernel 3: fused binarize of weight (blocks 0..OUT-1) and x
// (blocks OUT..OUT+BATCH-1). Bit-identical per-block programs.
__global__ __launch_bounds__(256) void binxw(
    const float* __restrict__ x, const float* __restrict__ mu,
    const float* __restrict__ aArr, const float* __restrict__ beta,
    const float* __restrict__ w,
    u8* __restrict__ x01, int* __restrict__ px,
    u8* __restrict__ w01, float* __restrict__ scale, int* __restrict__ pw) {
    __shared__ double redd[4];
    __shared__ int redi[4];
    __shared__ double bcast;
    int tid = threadIdx.x;
    int lane = tid & 63;
    int wv = tid >> 6;

    if (blockIdx.x < OUT) {
        // ---- weight path ----
        int o = blockIdx.x;
        const float4* row = (const float4*)(w + (size_t)o * IN);
        uchar4* o4 = (uchar4*)(w01 + (size_t)o * IN);

        float4 vs[4];
        float part = 0.f;
#pragma unroll
        for (int it = 0; it < 4; ++it) {
            vs[it] = row[it * 256 + tid];
            part += vs[it].x + vs[it].y + vs[it].z + vs[it].w;
        }
        double d = (double)part;
        for (int off = 32; off > 0; off >>= 1) d += __shfl_down(d, off, 64);
        if (lane == 0) redd[wv] = d;
        __syncthreads();
        if (tid == 0) bcast = (redd[0] + redd[1] + redd[2] + redd[3]) / (double)IN;
        __syncthreads();
        float mean = (float)bcast;

        float absacc = 0.f;
        int cnt = 0;
#pragma unroll
        for (int it = 0; it < 4; ++it) {
            float4 v = vs[it];
            float wcx = v.x - mean, wcy = v.y - mean, wcz = v.z - mean, wcw = v.w - mean;
            uchar4 ob;
            ob.x = (u8)(wcx > 0.f);
            ob.y = (u8)(wcy > 0.f);
            ob.z = (u8)(wcz > 0.f);
            ob.w = (u8)(wcw > 0.f);
            cnt += (int)ob.x + (int)ob.y + (int)ob.z + (int)ob.w;
            absacc += fminf(fabsf(wcx), 1.0f) + fminf(fabsf(wcy), 1.0f) +
                      fminf(fabsf(wcz), 1.0f) + fminf(fabsf(wcw), 1.0f);
            o4[it * 256 + tid] = ob;
        }
        double da = (double)absacc;
        for (int off = 32; off > 0; off >>= 1) da += __shfl_down(da, off, 64);
        for (int off = 32; off > 0; off >>= 1) cnt += __shfl_down(cnt, off, 64);
        if (lane == 0) { redd[wv] = da; redi[wv] = cnt; }
        __syncthreads();
        if (tid == 0) {
            scale[o] = (float)((redd[0] + redd[1] + redd[2] + redd[3]) / (double)IN);
            pw[o] = redi[0] + redi[1] + redi[2] + redi[3];
        }
    } else {
        // ---- activation path ----
        int r = blockIdx.x - OUT;
        const float4* row = (const float4*)(x + (size_t)r * IN);
        const float4* m4 = (const float4*)mu;
        const float4* a4 = (const float4*)aArr;
        const float4* b4 = (const float4*)beta;
        uchar4* o4 = (uchar4*)(x01 + (size_t)r * IN);
        int cnt = 0;
#pragma unroll
        for (int it = 0; it < IN / 1024; ++it) {   // 4 iters
            int q = it * 256 + tid;
            float4 v = row[q];
            float4 m = m4[q];
            float4 a = a4[q];
            float4 b = b4[q];
            uchar4 ob;
            ob.x = (u8)((v.x - m.x) * a.x + b.x > 0.f);
            ob.y = (u8)((v.y - m.y) * a.y + b.y > 0.f);
            ob.z = (u8)((v.z - m.z) * a.z + b.z > 0.f);
            ob.w = (u8)((v.w - m.w) * a.w + b.w > 0.f);
            cnt += (int)ob.x + (int)ob.y + (int)ob.z + (int)ob.w;
            o4[q] = ob;
        }
        for (int off = 32; off > 0; off >>= 1) cnt += __shfl_down(cnt, off, 64);
        if (lane == 0) redi[wv] = cnt;
        __syncthreads();
        if (tid == 0) px[r] = redi[0] + redi[1] + redi[2] + redi[3];
    }
}

// ---------------- Kernel 4: i8 MFMA GEMM, 256x256 tile, merged-region, BKB=128 ----
// One barrier region per 128-B K-tile: {STG(t+1) | 8 bf reads | per-i: 2 af reads
// + 8 MFMA | VM(0) | BAR}. 2 LDS buffers of 64 KiB (A 32K + B 32K) -- the
// R2-R5 PROVEN layout: 128-B rows, read slot = (4k+khi)^(row&7), staging via
// inverse-swizzled global source + linear LDS dest (0 bank conflicts, measured).
// WAR safety: buf (t+1)&1 was fully consumed (lgkm before each MFMA) before any
// wave crossed BAR(t-1); STG issues after it. RAW: VM(0) before BAR; the 8
// loads get the whole ~2600-cyc MMA region of latency cover. Compiler's
// fine-grained lgkmcnt interleaves later ds_reads under earlier MFMAs -> LDS
// pipe overlaps MFMA pipe instead of adding (R5 measured additive).
// dot_{+-1} = 4*acc - 2*px[r] - 2*pw[c] + IN
#define BKB 128
#define NKT (IN / BKB)     // 32

#define STG_A(t, q, p) __builtin_amdgcn_global_load_lds( \
    AS1(ag + (size_t)((q)*64 + slr) * IN + (t)*BKB + sswz), \
    AS3(lds + (p)*65536 + (q)*8192 + sdst), 16, 0, 0)
#define STG_B(t, q, p) __builtin_amdgcn_global_load_lds( \
    AS1(bg + (size_t)((q)*64 + slr) * IN + (t)*BKB + sswz), \
    AS3(lds + (p)*65536 + 32768 + (q)*8192 + sdst), 16, 0, 0)
#define STG8(t, p) do { \
    STG_A(t, 0, p); STG_A(t, 1, p); STG_A(t, 2, p); STG_A(t, 3, p); \
    STG_B(t, 0, p); STG_B(t, 1, p); STG_B(t, 2, p); STG_B(t, 3, p); \
} while (0)

// read+MMA for buffer p: bf[4][2] up front, then per-i {af k0,k1; 8 MFMA}
#define RD_MMA(p) do { \
    const u8* bp_ = lds + (p)*65536; \
    v4i bfr[4][2]; \
    _Pragma("unroll") for (int j_ = 0; j_ < 4; ++j_) \
    _Pragma("unroll") for (int k_ = 0; k_ < 2; ++k_) \
        bfr[j_][k_] = *(const v4i*)(bp_ + bBase + j_*2048 + swk[k_]); \
    _Pragma("unroll") for (int i_ = 0; i_ < 8; ++i_) { \
        v4i a0_ = *(const v4i*)(bp_ + aBase + i_*2048 + swk[0]); \
        v4i a1_ = *(const v4i*)(bp_ + aBase + i_*2048 + swk[1]); \
        __builtin_amdgcn_s_setprio(1); \
        _Pragma("unroll") for (int j_ = 0; j_ < 4; ++j_) { \
            acc[i_][j_] = __builtin_amdgcn_mfma_i32_16x16x64_i8( \
                a0_, bfr[j_][0], acc[i_][j_], 0, 0, 0); \
            acc[i_][j_] = __builtin_amdgcn_mfma_i32_16x16x64_i8( \
                a1_, bfr[j_][1], acc[i_][j_], 0, 0, 0); \
        } \
        __builtin_amdgcn_s_setprio(0); \
    } \
} while (0)

#define BAR() asm volatile("s_barrier" ::: "memory")
#define VM(n) asm volatile("s_waitcnt vmcnt(" #n ")" ::: "memory")

__global__ __launch_bounds__(512, 2) void bgemm_i8(
    const u8* __restrict__ x01, const u8* __restrict__ w01,
    const int* __restrict__ px, const int* __restrict__ pw,
    const float* __restrict__ scale, const float* __restrict__ bias,
    float* __restrict__ out) {
    __shared__ u8 lds[131072];   // 2 bufs x (A 32K + B 32K)

    int tid = threadIdx.x;
    int lane = tid & 63;
    int wave = tid >> 6;          // 0..7
    int wm = wave >> 2;           // 0..1  (row half: 128 rows)
    int wn = wave & 3;            // 0..3  (col quarter: 64 cols)

    // XCD-aware block swizzle (512 blocks, 512%8==0 -> bijective)
    int lin = blockIdx.y * (OUT / 256) + blockIdx.x;   // 0..511
    int swz = (lin & 7) * 64 + (lin >> 3);
    int colBlk = (swz & 15) * 256;
    int rowBlk = (swz >> 4) * 256;

    const u8* ag = x01 + (size_t)rowBlk * IN;
    const u8* bg = w01 + (size_t)colBlk * IN;

    // staging constants (linear LDS dest, inverse-swizzled global src) -- R5 verbatim
    int slr = tid >> 3;                 // row within 64-row unit
    int ss = tid & 7;                   // 16B slot
    int sswz = (ss ^ (slr & 7)) * 16;   // swizzled source byte offset
    int sdst = slr * 128 + ss * 16;     // linear LDS byte offset within unit

    // read constants -- R5 verbatim
    int lrow = lane & 15;
    int lhi = lane >> 4;                // k-chunk 0..3
    int llo = lane & 7;                 // == row&7 for the rows this lane reads
    int swk[2] = { ((lhi) ^ llo) * 16, ((4 + lhi) ^ llo) * 16 };
    int aBase = (wm * 128 + lrow) * 128;
    int bBase = 32768 + (wn * 64 + lrow) * 128;

    v4i acc[8][4];
#pragma unroll
    for (int i = 0; i < 8; ++i)
#pragma unroll
        for (int j = 0; j < 4; ++j) acc[i][j] = (v4i){0, 0, 0, 0};

    // ---- prologue: stage tile 0 ----
    STG8(0, 0);
    VM(0);
    BAR();

    // ---- steady regions t=0..29 (unroll 2 for compile-time buffer parity) ----
    for (int tt = 0; tt < 15; ++tt) {
        int t = 2 * tt;
        // region t (buf0): stage t+1 -> buf1
        STG8(t + 1, 1);
        RD_MMA(0);
        VM(0); BAR();
        // region t+1 (buf1): stage t+2 -> buf0
        STG8(t + 2, 0);
        RD_MMA(1);
        VM(0); BAR();
    }
    // region 30 (buf0): stage 31 -> buf1
    STG8(31, 1);
    RD_MMA(0);
    VM(0); BAR();
    // region 31 (buf1): no staging
    RD_MMA(1);

    // ---- epilogue ----
    int crow0 = lhi * 4;
    int ccol = lrow;
#pragma unroll
    for (int i = 0; i < 8; ++i) {
        int rbase = rowBlk + wm * 128 + i * 16 + crow0;
        int pxr[4];
#pragma unroll
        for (int rg = 0; rg < 4; ++rg) pxr[rg] = px[rbase + rg];
#pragma unroll
        for (int j = 0; j < 4; ++j) {
            int cb = colBlk + wn * 64 + j * 16 + ccol;
            float sc = scale[cb];
            float bs = bias[cb];
            int pwc = pw[cb];
#pragma unroll
            for (int rg = 0; rg < 4; ++rg) {
                int dot = 4 * acc[i][j][rg] - 2 * pxr[rg] - 2 * pwc + IN;
                float y = ((float)dot + bs) * sc;
                out[(size_t)(rbase + rg) * OUT + cb] = y > 0.f ? y : 0.f;
            }
        }
    }
}

extern "C" void kernel_launch(void* const* d_in, const int* in_sizes, int n_in,
                              void* d_out, int out_size, void* d_ws, size_t ws_size,
                              hipStream_t stream) {
    const float* x = (const float*)d_in[0];
    const float* gamma = (const float*)d_in[1];
    const float* beta = (const float*)d_in[2];
    const float* weight = (const float*)d_in[3];
    const float* bias = (const float*)d_in[4];
    float* out = (float*)d_out;

    char* w = (char*)d_ws;
    float* mu = (float*)(w);                    // 16 KB
    float* aArr = (float*)(w + 16384);          // 16 KB
    float* scale = (float*)(w + 32768);         // 16 KB
    int* px = (int*)(w + 49152);                // 32 KB
    int* pw = (int*)(w + 81920);                // 16 KB
    float* P1 = (float*)(w + (1 << 20));        // 1 MB
    float* P2 = (float*)(w + (2 << 20));        // 1 MB
    u8* x01 = (u8*)(w + (4 << 20));             // 32 MB
    u8* w01 = (u8*)(w + (36 << 20));            // 16 MB  (total 52 MB)

    colstat_partial<<<dim3(IN / 1024, NCHUNKS), 256, 0, stream>>>(x, P1, P2);
    colstat_final<<<dim3(IN / 256), 256, 0, stream>>>(P1, P2, gamma, mu, aArr);
    binxw<<<dim3(OUT + BATCH), 256, 0, stream>>>(x, mu, aArr, beta, weight,
                                                 x01, px, w01, scale, pw);
    bgemm_i8<<<dim3(OUT / 256, BATCH / 256), 512, 0, stream>>>(x01, w01, px, pw, scale, bias, out);
}